// Round 1
// 308.946 us; speedup vs baseline: 1.0456x; 1.0456x over previous
//
#include <hip/hip_runtime.h>

#define PLANE (384 * 384)
#define TH 16
#define TW 64
#define TROWS 18     // TH + 2 halo rows
#define TCOLS 66     // TW + 2 halo cols; row = 132 dwords, 132 % 32 = 4 (bank rotate)

typedef float f4_t __attribute__((ext_vector_type(4)));

#if __has_builtin(__builtin_amdgcn_sdot4)
__device__ __forceinline__ int sdot4(int a, int b, int c) {
    return __builtin_amdgcn_sdot4(a, b, c, false);
}
#else
__device__ __forceinline__ int sdot4(int a, int b, int c) {
    #pragma unroll
    for (int i = 0; i < 4; ++i)
        c += ((a << (24 - 8 * i)) >> 24) * ((b << (24 - 8 * i)) >> 24);
    return c;
}
#endif

// ---------------- Pass 1: abs-max of x (and of weight, in block 0) ----------
// Grid MUST be 2048 blocks x 256 threads: 9437184 float4 = exactly 18/thread.
__global__ __launch_bounds__(256) void amax_kernel(
    const float* __restrict__ x, const float* __restrict__ w,
    unsigned int* __restrict__ ws)
{
    __shared__ float red[4];
    const float4* x4 = (const float4*)x;
    const int tid = blockIdx.x * 256 + threadIdx.x;   // 0 .. 524287

    float m = 0.f;
    #pragma unroll
    for (int i = 0; i < 18; ++i) {
        float4 v = x4[tid + i * 524288];   // all 18 loads independent, in flight
        m = fmaxf(m, fmaxf(fmaxf(fabsf(v.x), fabsf(v.y)),
                           fmaxf(fabsf(v.z), fabsf(v.w))));
    }
    #pragma unroll
    for (int off = 32; off > 0; off >>= 1)
        m = fmaxf(m, __shfl_down(m, off, 64));
    if ((threadIdx.x & 63) == 0) red[threadIdx.x >> 6] = m;
    __syncthreads();
    if (threadIdx.x == 0) {
        float bm = fmaxf(fmaxf(red[0], red[1]), fmaxf(red[2], red[3]));
        atomicMax(&ws[0], __float_as_uint(bm));  // floats >= 0: uint-monotone
    }

    if (blockIdx.x == 0) {
        float mw = 0.f;
        for (int j = threadIdx.x; j < 576; j += 256)
            mw = fmaxf(mw, fabsf(w[j]));
        #pragma unroll
        for (int off = 32; off > 0; off >>= 1)
            mw = fmaxf(mw, __shfl_down(mw, off, 64));
        if ((threadIdx.x & 63) == 0)
            atomicMax(&ws[1], __float_as_uint(mw));
    }
}

// ------- Pass 2: quantize -> packed int8 -> sdot4 conv -> dequant + bias ----
// Block: 256 threads, one 16x64 output tile, all 8 output channels.
// LDS input tile: 18 x 66 px, each px = 8 channels packed as 2 dwords (int8x4).
// Staging: interior (cols 1..64) via aligned float4 loads, 4-px tasks;
//          halo cols 0,65 via scalar loads on wave 3.
// Output: nontemporal stores -> out does not evict x from L3; conv's x reads
//         hit Infinity Cache (warmed by amax pass).
__global__ __launch_bounds__(256) void conv_kernel(
    const float* __restrict__ x, const float* __restrict__ w,
    const float* __restrict__ bias, const unsigned int* __restrict__ ws,
    float* __restrict__ out)
{
    __shared__ __align__(16) unsigned sIn[TROWS * TCOLS * 2];  // 9504 B
    __shared__ __align__(16) unsigned sWq[9 * 8 * 2];          // [p][k][half], 576 B
    __shared__ float sB[8];

    const float amax_x = __uint_as_float(ws[0]);
    const float amax_w = __uint_as_float(ws[1]);
    const float s_x = 127.0f / amax_x;
    const float s_w = 127.0f / amax_w;
    const float inv = 1.0f / (s_x * s_w);

    const int bid = blockIdx.x;
    const int bx = bid % 6;             // 384/TW
    const int by = (bid / 6) % 24;      // 384/TH
    const int n  = bid / (6 * 24);
    const int h0 = by * TH;
    const int w0 = bx * TW;
    const int tid = threadIdx.x;

    // quantize + pack weights: w[k][c][p] -> sWq[p*16 + k*2 + h], bytes c=4h..4h+3
    if (tid < 144) {
        int h = tid & 1, k = (tid >> 1) & 7, p = tid >> 4;
        unsigned pk = 0;
        #pragma unroll
        for (int j = 0; j < 4; ++j) {
            int c = 4 * h + j;
            float qv = fminf(fmaxf(rintf(w[k * 72 + c * 9 + p] * s_w), -127.f), 127.f);
            int qi = (int)qv;
            pk |= ((unsigned)(qi & 0xff)) << (8 * j);
        }
        sWq[p * 16 + k * 2 + h] = pk;
    }
    if (tid < 8) sB[tid] = bias[tid];

    const float* xn = x + (long)n * 8 * PLANE;

    // Interior: 18 rows x 16 groups of 4 px, cols xx = 1+4g .. 4+4g.
    // gx0 = w0 + 4g is 16B-aligned (w0 % 64 == 0) -> aligned dwordx4 loads.
    for (int task = tid; task < 288; task += 256) {
        int yy = task >> 4;        // 0..17
        int g  = task & 15;        // 0..15
        int gy = h0 - 1 + yy;
        bool rowok = ((unsigned)gy < 384u);
        const float* rp = xn + (long)gy * 384 + (w0 + 4 * g);
        unsigned lo[4] = {0, 0, 0, 0}, hi[4] = {0, 0, 0, 0};
        if (rowok) {
            #pragma unroll
            for (int c = 0; c < 8; ++c) {
                f4_t v = *(const f4_t*)(rp + (long)c * PLANE);
                #pragma unroll
                for (int j = 0; j < 4; ++j) {
                    float qv = fminf(fmaxf(rintf(v[j] * s_x), -127.f), 127.f);
                    int qi = (int)qv;
                    unsigned b = ((unsigned)(qi & 0xff)) << (8 * (c & 3));
                    if (c < 4) lo[j] |= b; else hi[j] |= b;
                }
            }
        }
        int q0 = yy * TCOLS + 1 + 4 * g;
        #pragma unroll
        for (int j = 0; j < 4; ++j)
            *(uint2*)&sIn[2 * (q0 + j)] = make_uint2(lo[j], hi[j]);
    }

    // Halo: 18 rows x 2 cols (xx = 0 and 65), 36 px, on wave-3 threads.
    if (tid >= 220) {
        int t = tid - 220;               // 0..35
        int yy = t >> 1;                 // 0..17
        int xx = (t & 1) ? 65 : 0;
        int gy = h0 - 1 + yy;
        int gx = w0 - 1 + xx;
        bool ok = ((unsigned)gy < 384u) && ((unsigned)gx < 384u);
        long base = (long)gy * 384 + gx;
        unsigned lo = 0, hi = 0;
        if (ok) {
            #pragma unroll
            for (int c = 0; c < 8; ++c) {
                float v = xn[(long)c * PLANE + base];
                float qv = fminf(fmaxf(rintf(v * s_x), -127.f), 127.f);
                int qi = (int)qv;
                if (c < 4) lo |= ((unsigned)(qi & 0xff)) << (8 * c);
                else       hi |= ((unsigned)(qi & 0xff)) << (8 * (c - 4));
            }
        }
        *(uint2*)&sIn[2 * (yy * TCOLS + xx)] = make_uint2(lo, hi);
    }
    __syncthreads();

    const int ty = tid >> 4;   // 0..15 output row
    const int tx = tid & 15;   // output cols 4*tx .. 4*tx+3

    int acc[4][8];
    #pragma unroll
    for (int i = 0; i < 4; ++i)
        #pragma unroll
        for (int k = 0; k < 8; ++k) acc[i][k] = 0;

    #pragma unroll
    for (int r = 0; r < 3; ++r) {
        // 6 input px (12 dwords) via 3 x ds_read_b128; xx = 4*tx .. 4*tx+5
        const uint4* ip = (const uint4*)&sIn[((ty + r) * TCOLS + 4 * tx) * 2];
        uint4 i0 = ip[0], i1 = ip[1], i2 = ip[2];
        unsigned d[12] = {i0.x, i0.y, i0.z, i0.w,
                          i1.x, i1.y, i1.z, i1.w,
                          i2.x, i2.y, i2.z, i2.w};
        #pragma unroll
        for (int s = 0; s < 3; ++s) {
            const uint4* wp = (const uint4*)&sWq[(r * 3 + s) * 16];  // broadcast
            uint4 wa = wp[0], wb = wp[1], wc = wp[2], wd = wp[3];
            unsigned wk[16] = {wa.x, wa.y, wa.z, wa.w, wb.x, wb.y, wb.z, wb.w,
                               wc.x, wc.y, wc.z, wc.w, wd.x, wd.y, wd.z, wd.w};
            #pragma unroll
            for (int k = 0; k < 8; ++k)
                #pragma unroll
                for (int i = 0; i < 4; ++i)
                    acc[i][k] = sdot4((int)d[2 * (i + s) + 1], (int)wk[2 * k + 1],
                                sdot4((int)d[2 * (i + s)],     (int)wk[2 * k],
                                      acc[i][k]));
        }
    }

    float* on = out + (long)n * 8 * PLANE + (long)(h0 + ty) * 384 + (w0 + 4 * tx);
    #pragma unroll
    for (int k = 0; k < 8; ++k) {
        f4_t o;
        o.x = fmaf((float)acc[0][k], inv, sB[k]);
        o.y = fmaf((float)acc[1][k], inv, sB[k]);
        o.z = fmaf((float)acc[2][k], inv, sB[k]);
        o.w = fmaf((float)acc[3][k], inv, sB[k]);
        __builtin_nontemporal_store(o, (f4_t*)(on + (long)k * PLANE));
    }
}

extern "C" void kernel_launch(void* const* d_in, const int* in_sizes, int n_in,
                              void* d_out, int out_size, void* d_ws, size_t ws_size,
                              hipStream_t stream) {
    const float* x   = (const float*)d_in[0];
    const float* w   = (const float*)d_in[1];
    const float* b   = (const float*)d_in[2];
    float* out       = (float*)d_out;
    unsigned int* ws = (unsigned int*)d_ws;

    // d_ws is poisoned 0xAA (huge as uint) -> zero the two amax slots first.
    hipMemsetAsync(ws, 0, 2 * sizeof(unsigned int), stream);
    amax_kernel<<<2048, 256, 0, stream>>>(x, w, ws);
    conv_kernel<<<32 * 24 * 6, 256, 0, stream>>>(x, w, b, ws, out);
}

// Round 2
// 300.585 us; speedup vs baseline: 1.0747x; 1.0278x over previous
//
#include <hip/hip_runtime.h>

#define PLANE (384 * 384)
#define TH 16
#define TW 64
#define TROWS 18     // TH + 2 halo rows
#define TCOLS 66     // TW + 2 halo cols; row = 132 dwords, 132 % 32 = 4 (bank rotate)

typedef float f4_t __attribute__((ext_vector_type(4)));

#if __has_builtin(__builtin_amdgcn_sdot4)
__device__ __forceinline__ int sdot4(int a, int b, int c) {
    return __builtin_amdgcn_sdot4(a, b, c, false);
}
#else
__device__ __forceinline__ int sdot4(int a, int b, int c) {
    #pragma unroll
    for (int i = 0; i < 4; ++i)
        c += ((a << (24 - 8 * i)) >> 24) * ((b << (24 - 8 * i)) >> 24);
    return c;
}
#endif

// ---------------- Pass 1: abs-max of x (and of weight, in block 0) ----------
// Grid MUST be 2048 blocks x 256 threads: 9437184 float4 = exactly 18/thread.
__global__ __launch_bounds__(256) void amax_kernel(
    const float* __restrict__ x, const float* __restrict__ w,
    unsigned int* __restrict__ ws)
{
    __shared__ float red[4];
    const float4* x4 = (const float4*)x;
    const int tid = blockIdx.x * 256 + threadIdx.x;   // 0 .. 524287

    float m = 0.f;
    #pragma unroll
    for (int i = 0; i < 18; ++i) {
        float4 v = x4[tid + i * 524288];   // all 18 loads independent, in flight
        m = fmaxf(m, fmaxf(fmaxf(fabsf(v.x), fabsf(v.y)),
                           fmaxf(fabsf(v.z), fabsf(v.w))));
    }
    #pragma unroll
    for (int off = 32; off > 0; off >>= 1)
        m = fmaxf(m, __shfl_down(m, off, 64));
    if ((threadIdx.x & 63) == 0) red[threadIdx.x >> 6] = m;
    __syncthreads();
    if (threadIdx.x == 0) {
        float bm = fmaxf(fmaxf(red[0], red[1]), fmaxf(red[2], red[3]));
        atomicMax(&ws[0], __float_as_uint(bm));  // floats >= 0: uint-monotone
    }

    if (blockIdx.x == 0) {
        float mw = 0.f;
        for (int j = threadIdx.x; j < 576; j += 256)
            mw = fmaxf(mw, fabsf(w[j]));
        #pragma unroll
        for (int off = 32; off > 0; off >>= 1)
            mw = fmaxf(mw, __shfl_down(mw, off, 64));
        if ((threadIdx.x & 63) == 0)
            atomicMax(&ws[1], __float_as_uint(mw));
    }
}

// ------- Pass 2: quantize x once into pixel-packed int8 q[n][y][x][8ch] ----
// Thread: 4 px, 8 channels each. x reads hit L3 (warmed by amax). q = 37.7 MB,
// written normally (NOT nontemporal) so conv reads it from L2/L3.
// Grid MUST be 4608 x 256: 4,718,592 px / 4 per thread.
__global__ __launch_bounds__(256) void quant_kernel(
    const float* __restrict__ x, const unsigned int* __restrict__ ws,
    unsigned* __restrict__ q)
{
    const float s_x = 127.0f / __uint_as_float(ws[0]);
    const int t = blockIdx.x * 256 + threadIdx.x;   // 0 .. 1,179,647
    const int g = t * 4;                            // first pixel (over n*PLANE)
    const int n = g / PLANE;
    const int r = g - n * PLANE;
    const float* xp = x + (long)n * (8 * PLANE) + r;

    unsigned lo[4] = {0, 0, 0, 0}, hi[4] = {0, 0, 0, 0};
    #pragma unroll
    for (int c = 0; c < 8; ++c) {
        f4_t v = *(const f4_t*)(xp + (long)c * PLANE);
        #pragma unroll
        for (int j = 0; j < 4; ++j) {
            float qv = fminf(fmaxf(rintf(v[j] * s_x), -127.f), 127.f);
            int qi = (int)qv;
            unsigned b = ((unsigned)(qi & 0xff)) << (8 * (c & 3));
            if (c < 4) lo[j] |= b; else hi[j] |= b;
        }
    }
    uint4* qp = (uint4*)q + (long)t * 2;   // 32 B per thread, contiguous
    qp[0] = make_uint4(lo[0], hi[0], lo[1], hi[1]);
    qp[1] = make_uint4(lo[2], hi[2], lo[3], hi[3]);
}

// ------- Pass 3: int8 conv from packed q -> sdot4 -> dequant + bias --------
// Staging is now pure byte-copy: 576 dwordx4 + 36 b64 loads per block, no math.
__global__ __launch_bounds__(256) void conv_kernel_q(
    const unsigned* __restrict__ q, const float* __restrict__ w,
    const float* __restrict__ bias, const unsigned int* __restrict__ ws,
    float* __restrict__ out)
{
    __shared__ __align__(16) unsigned sIn[TROWS * TCOLS * 2];  // 9504 B
    __shared__ __align__(16) unsigned sWq[9 * 8 * 2];          // [p][k][half]
    __shared__ float sB[8];

    const float amax_x = __uint_as_float(ws[0]);
    const float amax_w = __uint_as_float(ws[1]);
    const float s_x = 127.0f / amax_x;
    const float s_w = 127.0f / amax_w;
    const float inv = 1.0f / (s_x * s_w);

    const int bid = blockIdx.x;
    const int bx = bid % 6;             // 384/TW
    const int by = (bid / 6) % 24;      // 384/TH
    const int n  = bid / (6 * 24);
    const int h0 = by * TH;
    const int w0 = bx * TW;
    const int tid = threadIdx.x;

    // quantize + pack weights: w[k][c][p] -> sWq[p*16 + k*2 + h], bytes c=4h..4h+3
    if (tid < 144) {
        int h = tid & 1, k = (tid >> 1) & 7, p = tid >> 4;
        unsigned pk = 0;
        #pragma unroll
        for (int j = 0; j < 4; ++j) {
            int c = 4 * h + j;
            float qv = fminf(fmaxf(rintf(w[k * 72 + c * 9 + p] * s_w), -127.f), 127.f);
            int qi = (int)qv;
            pk |= ((unsigned)(qi & 0xff)) << (8 * j);
        }
        sWq[p * 16 + k * 2 + h] = pk;
    }
    if (tid < 8) sB[tid] = bias[tid];

    const unsigned* qn = q + (long)n * PLANE * 2;

    // Interior: 18 rows x 32 segments of 2 px (16 B, aligned) each.
    for (int t = tid; t < 576; t += 256) {
        int yy = t >> 5;                 // 0..17
        int seg = t & 31;                // 0..31
        int gy = h0 - 1 + yy;
        uint4 v = make_uint4(0, 0, 0, 0);
        if ((unsigned)gy < 384u)
            v = *(const uint4*)(qn + ((long)gy * 384 + (w0 + 2 * seg)) * 2);
        int p = yy * TCOLS + 1 + 2 * seg;
        *(uint2*)&sIn[2 * p]     = make_uint2(v.x, v.y);
        *(uint2*)&sIn[2 * p + 2] = make_uint2(v.z, v.w);
    }
    // Halo: 18 rows x 2 cols (xx = 0 and 65), 36 px, on wave-3 threads.
    if (tid >= 220) {
        int t = tid - 220;               // 0..35
        int yy = t >> 1;
        int xx = (t & 1) ? 65 : 0;
        int gy = h0 - 1 + yy;
        int gx = w0 - 1 + xx;
        uint2 v = make_uint2(0, 0);
        if (((unsigned)gy < 384u) && ((unsigned)gx < 384u))
            v = *(const uint2*)(qn + ((long)gy * 384 + gx) * 2);
        *(uint2*)&sIn[2 * (yy * TCOLS + xx)] = v;
    }
    __syncthreads();

    const int ty = tid >> 4;   // 0..15 output row
    const int tx = tid & 15;   // output cols 4*tx .. 4*tx+3

    int acc[4][8];
    #pragma unroll
    for (int i = 0; i < 4; ++i)
        #pragma unroll
        for (int k = 0; k < 8; ++k) acc[i][k] = 0;

    #pragma unroll
    for (int r = 0; r < 3; ++r) {
        // 6 input px (12 dwords) via 3 x ds_read_b128; xx = 4*tx .. 4*tx+5
        const uint4* ip = (const uint4*)&sIn[((ty + r) * TCOLS + 4 * tx) * 2];
        uint4 i0 = ip[0], i1 = ip[1], i2 = ip[2];
        unsigned d[12] = {i0.x, i0.y, i0.z, i0.w,
                          i1.x, i1.y, i1.z, i1.w,
                          i2.x, i2.y, i2.z, i2.w};
        #pragma unroll
        for (int s = 0; s < 3; ++s) {
            const uint4* wp = (const uint4*)&sWq[(r * 3 + s) * 16];  // broadcast
            uint4 wa = wp[0], wb = wp[1], wc = wp[2], wd = wp[3];
            unsigned wk[16] = {wa.x, wa.y, wa.z, wa.w, wb.x, wb.y, wb.z, wb.w,
                               wc.x, wc.y, wc.z, wc.w, wd.x, wd.y, wd.z, wd.w};
            #pragma unroll
            for (int k = 0; k < 8; ++k)
                #pragma unroll
                for (int i = 0; i < 4; ++i)
                    acc[i][k] = sdot4((int)d[2 * (i + s) + 1], (int)wk[2 * k + 1],
                                sdot4((int)d[2 * (i + s)],     (int)wk[2 * k],
                                      acc[i][k]));
        }
    }

    float* on = out + (long)n * 8 * PLANE + (long)(h0 + ty) * 384 + (w0 + 4 * tx);
    #pragma unroll
    for (int k = 0; k < 8; ++k) {
        f4_t o;
        o.x = fmaf((float)acc[0][k], inv, sB[k]);
        o.y = fmaf((float)acc[1][k], inv, sB[k]);
        o.z = fmaf((float)acc[2][k], inv, sB[k]);
        o.w = fmaf((float)acc[3][k], inv, sB[k]);
        __builtin_nontemporal_store(o, (f4_t*)(on + (long)k * PLANE));
    }
}

// ------- Fallback: fused quantize+conv (round-1 kernel), if ws too small ----
__global__ __launch_bounds__(256) void conv_kernel_f32(
    const float* __restrict__ x, const float* __restrict__ w,
    const float* __restrict__ bias, const unsigned int* __restrict__ ws,
    float* __restrict__ out)
{
    __shared__ __align__(16) unsigned sIn[TROWS * TCOLS * 2];
    __shared__ __align__(16) unsigned sWq[9 * 8 * 2];
    __shared__ float sB[8];

    const float amax_x = __uint_as_float(ws[0]);
    const float amax_w = __uint_as_float(ws[1]);
    const float s_x = 127.0f / amax_x;
    const float s_w = 127.0f / amax_w;
    const float inv = 1.0f / (s_x * s_w);

    const int bid = blockIdx.x;
    const int bx = bid % 6;
    const int by = (bid / 6) % 24;
    const int n  = bid / (6 * 24);
    const int h0 = by * TH;
    const int w0 = bx * TW;
    const int tid = threadIdx.x;

    if (tid < 144) {
        int h = tid & 1, k = (tid >> 1) & 7, p = tid >> 4;
        unsigned pk = 0;
        #pragma unroll
        for (int j = 0; j < 4; ++j) {
            int c = 4 * h + j;
            float qv = fminf(fmaxf(rintf(w[k * 72 + c * 9 + p] * s_w), -127.f), 127.f);
            int qi = (int)qv;
            pk |= ((unsigned)(qi & 0xff)) << (8 * j);
        }
        sWq[p * 16 + k * 2 + h] = pk;
    }
    if (tid < 8) sB[tid] = bias[tid];

    const float* xn = x + (long)n * 8 * PLANE;

    for (int task = tid; task < 288; task += 256) {
        int yy = task >> 4;
        int g  = task & 15;
        int gy = h0 - 1 + yy;
        bool rowok = ((unsigned)gy < 384u);
        const float* rp = xn + (long)gy * 384 + (w0 + 4 * g);
        unsigned lo[4] = {0, 0, 0, 0}, hi[4] = {0, 0, 0, 0};
        if (rowok) {
            #pragma unroll
            for (int c = 0; c < 8; ++c) {
                f4_t v = *(const f4_t*)(rp + (long)c * PLANE);
                #pragma unroll
                for (int j = 0; j < 4; ++j) {
                    float qv = fminf(fmaxf(rintf(v[j] * s_x), -127.f), 127.f);
                    int qi = (int)qv;
                    unsigned b = ((unsigned)(qi & 0xff)) << (8 * (c & 3));
                    if (c < 4) lo[j] |= b; else hi[j] |= b;
                }
            }
        }
        int q0 = yy * TCOLS + 1 + 4 * g;
        #pragma unroll
        for (int j = 0; j < 4; ++j)
            *(uint2*)&sIn[2 * (q0 + j)] = make_uint2(lo[j], hi[j]);
    }

    if (tid >= 220) {
        int t = tid - 220;
        int yy = t >> 1;
        int xx = (t & 1) ? 65 : 0;
        int gy = h0 - 1 + yy;
        int gx = w0 - 1 + xx;
        bool ok = ((unsigned)gy < 384u) && ((unsigned)gx < 384u);
        long base = (long)gy * 384 + gx;
        unsigned lo = 0, hi = 0;
        if (ok) {
            #pragma unroll
            for (int c = 0; c < 8; ++c) {
                float v = xn[(long)c * PLANE + base];
                float qv = fminf(fmaxf(rintf(v * s_x), -127.f), 127.f);
                int qi = (int)qv;
                if (c < 4) lo |= ((unsigned)(qi & 0xff)) << (8 * c);
                else       hi |= ((unsigned)(qi & 0xff)) << (8 * (c - 4));
            }
        }
        *(uint2*)&sIn[2 * (yy * TCOLS + xx)] = make_uint2(lo, hi);
    }
    __syncthreads();

    const int ty = tid >> 4;
    const int tx = tid & 15;

    int acc[4][8];
    #pragma unroll
    for (int i = 0; i < 4; ++i)
        #pragma unroll
        for (int k = 0; k < 8; ++k) acc[i][k] = 0;

    #pragma unroll
    for (int r = 0; r < 3; ++r) {
        const uint4* ip = (const uint4*)&sIn[((ty + r) * TCOLS + 4 * tx) * 2];
        uint4 i0 = ip[0], i1 = ip[1], i2 = ip[2];
        unsigned d[12] = {i0.x, i0.y, i0.z, i0.w,
                          i1.x, i1.y, i1.z, i1.w,
                          i2.x, i2.y, i2.z, i2.w};
        #pragma unroll
        for (int s = 0; s < 3; ++s) {
            const uint4* wp = (const uint4*)&sWq[(r * 3 + s) * 16];
            uint4 wa = wp[0], wb = wp[1], wc = wp[2], wd = wp[3];
            unsigned wk[16] = {wa.x, wa.y, wa.z, wa.w, wb.x, wb.y, wb.z, wb.w,
                               wc.x, wc.y, wc.z, wc.w, wd.x, wd.y, wd.z, wd.w};
            #pragma unroll
            for (int k = 0; k < 8; ++k)
                #pragma unroll
                for (int i = 0; i < 4; ++i)
                    acc[i][k] = sdot4((int)d[2 * (i + s) + 1], (int)wk[2 * k + 1],
                                sdot4((int)d[2 * (i + s)],     (int)wk[2 * k],
                                      acc[i][k]));
        }
    }

    float* on = out + (long)n * 8 * PLANE + (long)(h0 + ty) * 384 + (w0 + 4 * tx);
    #pragma unroll
    for (int k = 0; k < 8; ++k) {
        f4_t o;
        o.x = fmaf((float)acc[0][k], inv, sB[k]);
        o.y = fmaf((float)acc[1][k], inv, sB[k]);
        o.z = fmaf((float)acc[2][k], inv, sB[k]);
        o.w = fmaf((float)acc[3][k], inv, sB[k]);
        __builtin_nontemporal_store(o, (f4_t*)(on + (long)k * PLANE));
    }
}

extern "C" void kernel_launch(void* const* d_in, const int* in_sizes, int n_in,
                              void* d_out, int out_size, void* d_ws, size_t ws_size,
                              hipStream_t stream) {
    const float* x   = (const float*)d_in[0];
    const float* w   = (const float*)d_in[1];
    const float* b   = (const float*)d_in[2];
    float* out       = (float*)d_out;
    unsigned int* ws = (unsigned int*)d_ws;

    // d_ws is poisoned 0xAA (huge as uint) -> zero the two amax slots first.
    hipMemsetAsync(ws, 0, 2 * sizeof(unsigned int), stream);
    amax_kernel<<<2048, 256, 0, stream>>>(x, w, ws);

    const size_t QOFF   = 64;                          // bytes, keep q 16B-aligned
    const size_t QBYTES = (size_t)32 * PLANE * 8;      // 37,748,736 B
    if (ws_size >= QOFF + QBYTES) {
        unsigned* q = (unsigned*)((char*)d_ws + QOFF);
        quant_kernel<<<4608, 256, 0, stream>>>(x, ws, q);
        conv_kernel_q<<<4608, 256, 0, stream>>>(q, w, b, ws, out);
    } else {
        conv_kernel_f32<<<4608, 256, 0, stream>>>(x, w, b, ws, out);
    }
}